// Round 6
// baseline (364.044 us; speedup 1.0000x reference)
//
#include <hip/hip_runtime.h>
#include <math.h>

// DrugEncoder: 2x TransformerConv (heads=1) + global mean pool.
// N=50000 nodes, E=800000 edges, G=512 graphs, D_IN=64, D_HID=D_EMB=128.
//
// R6: edge_agg defer-max (rescale only when max grows >8), bf16 pre-scaled q,
//     fused memset + cvt_x folded into prep_w. GEMMs: bf16 MFMA (R5).

constexpr int D1 = 64;
constexpr int DH = 128;
constexpr int SCHUNK = 1024;
constexpr float QSCALE = 0.08838834764831845f;  // 1/sqrt(128)

typedef __attribute__((ext_vector_type(8))) short short8v;
typedef __attribute__((ext_vector_type(4))) float f32x4;

__device__ inline unsigned short bf16r(float f) {
  unsigned u = __float_as_uint(f);
  return (unsigned short)((u + 0x7fffu + ((u >> 16) & 1u)) >> 16);
}

__device__ inline unsigned pack_bf16_2(float a, float b) {
  return (unsigned)bf16r(a) | ((unsigned)bf16r(b) << 16);
}

// ---------------- CSR build ----------------

__global__ void hist_kernel(const int* __restrict__ dst, int* __restrict__ deg, int E) {
  int e = blockIdx.x * blockDim.x + threadIdx.x;
  if (e < E) atomicAdd(&deg[dst[e]], 1);
}

__global__ void scan_chunks(const int* __restrict__ deg, int* __restrict__ incl,
                            int* __restrict__ sums, int N) {
  __shared__ int lds[256];
  int b = blockIdx.x, tid = threadIdx.x;
  int base = b * SCHUNK + tid * 4;
  int e0 = (base + 0 < N) ? deg[base + 0] : 0;
  int e1 = (base + 1 < N) ? deg[base + 1] : 0;
  int e2 = (base + 2 < N) ? deg[base + 2] : 0;
  int e3 = (base + 3 < N) ? deg[base + 3] : 0;
  int t0 = e0, t1 = t0 + e1, t2 = t1 + e2, t3 = t2 + e3;
  lds[tid] = t3;
  __syncthreads();
  for (int off = 1; off < 256; off <<= 1) {
    int v = (tid >= off) ? lds[tid - off] : 0;
    __syncthreads();
    lds[tid] += v;
    __syncthreads();
  }
  int excl = (tid > 0) ? lds[tid - 1] : 0;
  if (base + 0 < N) incl[base + 0] = t0 + excl;
  if (base + 1 < N) incl[base + 1] = t1 + excl;
  if (base + 2 < N) incl[base + 2] = t2 + excl;
  if (base + 3 < N) incl[base + 3] = t3 + excl;
  if (tid == 255) sums[b] = lds[255];
}

__global__ void scan_top(const int* __restrict__ sums, int* __restrict__ offs, int nch) {
  if (threadIdx.x == 0 && blockIdx.x == 0) {
    int run = 0;
    for (int i = 0; i < nch; ++i) { offs[i] = run; run += sums[i]; }
  }
}

__global__ void finalize_rowptr(const int* __restrict__ incl, const int* __restrict__ offs,
                                int* __restrict__ rowptr, int N) {
  int n = blockIdx.x * blockDim.x + threadIdx.x;
  if (n < N) rowptr[n + 1] = incl[n] + offs[n / SCHUNK];
  if (n == 0) rowptr[0] = 0;
}

__global__ void fill_csr(const int* __restrict__ src, const int* __restrict__ dst,
                         const int* __restrict__ rowptr, int* __restrict__ fill,
                         int* __restrict__ csr_src, int E) {
  int e = blockIdx.x * blockDim.x + threadIdx.x;
  if (e < E) {
    int d = dst[e];
    int pos = rowptr[d] + atomicAdd(&fill[d], 1);
    csr_src[pos] = src[e];
  }
}

// ---------------- prep: W -> transposed bf16 (y<8), x -> bf16 (y==8) ----------------

__global__ void prep_w(const float* w0, const float* w1, const float* w2, const float* w3,
                       const float* w4, const float* w5, const float* w6, const float* w7,
                       unsigned short* t0, unsigned short* t1, unsigned short* t2,
                       unsigned short* t3, unsigned short* t4, unsigned short* t5,
                       unsigned short* t6, unsigned short* t7,
                       const float4* __restrict__ x, uint2* __restrict__ xb, int n4) {
  int m = blockIdx.y;
  int stride = gridDim.x * blockDim.x;
  int start = blockIdx.x * blockDim.x + threadIdx.x;
  if (m == 8) {
    for (int i = start; i < n4; i += stride) {
      float4 v = x[i];
      uint2 o;
      o.x = pack_bf16_2(v.x, v.y);
      o.y = pack_bf16_2(v.z, v.w);
      xb[i] = o;
    }
    return;
  }
  const float* W;
  unsigned short* T;
  switch (m) {
    case 0: W = w0; T = t0; break;
    case 1: W = w1; T = t1; break;
    case 2: W = w2; T = t2; break;
    case 3: W = w3; T = t3; break;
    case 4: W = w4; T = t4; break;
    case 5: W = w5; T = t5; break;
    case 6: W = w6; T = t6; break;
    default: W = w7; T = t7; break;
  }
  int din = (m < 4) ? 64 : 128;
  int total = din * 128;
  for (int i = start; i < total; i += stride) {
    int r = i >> 7, c = i & 127;  // W[r][c]
    T[c * din + r] = bf16r(W[i]);
  }
}

// ---------------- bf16 MFMA 4-way linear ----------------
// grid (ceil(N/64), 4). y: 0=q(bf16, pre-scaled by 1/sqrt(128)) 1=k(->kv lo)
// 2=v(->kv hi) 3=skip(fp32).
// A: xb[64 x DIN] bf16 LDS (padded stride DS=DIN+8). B: Wt_y[128 x DIN] same.
// Wave w: rows 16w..16w+15 x 128 cols: 8 nf x DIN/32 ks mfma_f32_16x16x32_bf16.

template <int DIN>
__global__ __launch_bounds__(256) void gemm4(
    const unsigned short* __restrict__ xb, int N,
    const unsigned short* __restrict__ Wt0, const float* __restrict__ B0,
    const unsigned short* __restrict__ Wt1, const float* __restrict__ B1,
    const unsigned short* __restrict__ Wt2, const float* __restrict__ B2,
    const unsigned short* __restrict__ Wt3, const float* __restrict__ B3,
    unsigned short* __restrict__ Qb, unsigned short* __restrict__ KV,
    float* __restrict__ Os) {
  constexpr int DS = DIN + 8;
  __shared__ __align__(16) unsigned short As[64 * DS];
  __shared__ __align__(16) unsigned short Bs[128 * DS];
  const unsigned short* Wt;
  const float* Bias;
  int y = blockIdx.y;
  switch (y) {
    case 0: Wt = Wt0; Bias = B0; break;
    case 1: Wt = Wt1; Bias = B1; break;
    case 2: Wt = Wt2; Bias = B2; break;
    default: Wt = Wt3; Bias = B3; break;
  }
  int tid = threadIdx.x;
  int n0 = blockIdx.x * 64;

  constexpr int ACH = 64 * DIN / 8;   // 16B chunks
  constexpr int CPR = DIN / 8;        // chunks per row
#pragma unroll
  for (int c = tid; c < ACH; c += 256) {
    int row = c / CPR, c8 = c - row * CPR;
    int n = n0 + row;
    uint4 val = {0u, 0u, 0u, 0u};
    if (n < N) val = *(const uint4*)&xb[(size_t)n * DIN + c8 * 8];
    *(uint4*)&As[row * DS + c8 * 8] = val;
  }
  constexpr int BCH = 128 * DIN / 8;
#pragma unroll
  for (int c = tid; c < BCH; c += 256) {
    int row = c / CPR, c8 = c - row * CPR;
    uint4 val = *(const uint4*)&Wt[(size_t)row * DIN + c8 * 8];
    *(uint4*)&Bs[row * DS + c8 * 8] = val;
  }
  __syncthreads();

  int w = tid >> 6, lane = tid & 63, lr = lane & 15, lg = lane >> 4;
  constexpr int KS = DIN / 32;
  short8v a[KS];
#pragma unroll
  for (int ks = 0; ks < KS; ++ks)
    a[ks] = *(const short8v*)&As[(16 * w + lr) * DS + ks * 32 + lg * 8];

  f32x4 acc[8];
#pragma unroll
  for (int nf = 0; nf < 8; ++nf) acc[nf] = (f32x4){0.f, 0.f, 0.f, 0.f};

#pragma unroll
  for (int ks = 0; ks < KS; ++ks) {
#pragma unroll
    for (int nf = 0; nf < 8; ++nf) {
      short8v b = *(const short8v*)&Bs[(nf * 16 + lr) * DS + ks * 32 + lg * 8];
      acc[nf] = __builtin_amdgcn_mfma_f32_16x16x32_bf16(a[ks], b, acc[nf], 0, 0, 0);
    }
  }

  int rbase = n0 + 16 * w + lg * 4;
#pragma unroll
  for (int nf = 0; nf < 8; ++nf) {
    int col = nf * 16 + lr;
    float bias = Bias[col];
    if (y == 0) {
#pragma unroll
      for (int r = 0; r < 4; ++r) {
        int n = rbase + r;
        if (n < N) Qb[(size_t)n * 128 + col] = bf16r((acc[nf][r] + bias) * QSCALE);
      }
    } else if (y == 3) {
#pragma unroll
      for (int r = 0; r < 4; ++r) {
        int n = rbase + r;
        if (n < N) Os[(size_t)n * 128 + col] = acc[nf][r] + bias;
      }
    } else {
      int off = (col >> 2) * 8 + (col & 3) + ((y == 2) ? 4 : 0);
#pragma unroll
      for (int r = 0; r < 4; ++r) {
        int n = rbase + r;
        if (n < N) KV[(size_t)n * 256 + off] = bf16r(acc[nf][r] + bias);
      }
    }
  }
}

// ---------------- edge aggregation ----------------
// One wave per dst node; 2 x 32-lane deferred-max online-softmax streams over
// alternating edges, merged at end. kv slot l = {k[4l..4l+3], v[4l..4l+3]} bf16.
// q is bf16, pre-scaled by 1/sqrt(128). Rescale only when max grows by >8.

template <bool RELU, bool OUTBF16>
__global__ __launch_bounds__(256) void edge_agg2(
    const unsigned short* __restrict__ qb, const uint4* __restrict__ kv,
    const int* __restrict__ rowptr, const int* __restrict__ csr_src,
    const float* skip, void* outp, int N) {
  int tid = threadIdx.x;
  int lane = tid & 63;
  int wv = tid >> 6;
  int n = blockIdx.x * 4 + wv;
  if (n >= N) return;
  int g = lane >> 5;
  int l = lane & 31;
  uint2 qp = *(const uint2*)&qb[(size_t)n * 128 + 4 * l];
  float qx = __uint_as_float(qp.x << 16);
  float qy = __uint_as_float(qp.x & 0xffff0000u);
  float qz = __uint_as_float(qp.y << 16);
  float qw = __uint_as_float(qp.y & 0xffff0000u);
  int beg = rowptr[n];
  int deg = rowptr[n + 1] - beg;
  float m = -INFINITY, lsum = 0.f;
  float a0 = 0.f, a1 = 0.f, a2 = 0.f, a3 = 0.f;
  int cnt = (deg - g + 1) >> 1;
  const int* cp = csr_src + beg + g;
  uint4 kv0 = {0, 0, 0, 0}, kv1 = {0, 0, 0, 0};
  if (cnt >= 1) kv0 = kv[(size_t)cp[0] * 32 + l];
  if (cnt >= 2) kv1 = kv[(size_t)cp[2] * 32 + l];
  for (int it = 0; it < cnt; ++it) {
    uint4 cur = kv0;
    kv0 = kv1;
    if (it + 2 < cnt) kv1 = kv[(size_t)cp[2 * (it + 2)] * 32 + l];
    float k0 = __uint_as_float(cur.x << 16);
    float k1 = __uint_as_float(cur.x & 0xffff0000u);
    float k2 = __uint_as_float(cur.y << 16);
    float k3 = __uint_as_float(cur.y & 0xffff0000u);
    float d = qx * k0 + qy * k1 + qz * k2 + qw * k3;
#pragma unroll
    for (int off = 1; off < 32; off <<= 1) d += __shfl_xor(d, off);
    float v0 = __uint_as_float(cur.z << 16);
    float v1 = __uint_as_float(cur.z & 0xffff0000u);
    float v2 = __uint_as_float(cur.w << 16);
    float v3 = __uint_as_float(cur.w & 0xffff0000u);
    if (d > m + 8.f) {        // rare: new max beyond slack -> rescale
      float cf = __expf(m - d);
      lsum = lsum * cf + 1.f;
      a0 = a0 * cf + v0;
      a1 = a1 * cf + v1;
      a2 = a2 * cf + v2;
      a3 = a3 * cf + v3;
      m = d;
    } else {                  // common: accumulate against stale max
      float ef = __expf(d - m);
      lsum += ef;
      a0 += ef * v0;
      a1 += ef * v1;
      a2 += ef * v2;
      a3 += ef * v3;
    }
  }
  float m2 = __shfl_xor(m, 32);
  float L2 = __shfl_xor(lsum, 32);
  float b0 = __shfl_xor(a0, 32);
  float b1 = __shfl_xor(a1, 32);
  float b2 = __shfl_xor(a2, 32);
  float b3 = __shfl_xor(a3, 32);
  if (lane < 32) {
    float ox0 = 0.f, ox1 = 0.f, ox2 = 0.f, ox3 = 0.f;
    if (deg > 0) {
      float M = fmaxf(m, m2);
      float c1 = __expf(m - M);
      float c2 = __expf(m2 - M);
      float rl = 1.f / (lsum * c1 + L2 * c2 + 1e-16f);
      ox0 = (a0 * c1 + b0 * c2) * rl;
      ox1 = (a1 * c1 + b1 * c2) * rl;
      ox2 = (a2 * c1 + b2 * c2) * rl;
      ox3 = (a3 * c1 + b3 * c2) * rl;
    }
    const float* sp = skip + (size_t)n * 128 + 4 * l;
    float4 o = *(const float4*)sp;
    o.x += ox0; o.y += ox1; o.z += ox2; o.w += ox3;
    if (RELU) {
      o.x = fmaxf(o.x, 0.f);
      o.y = fmaxf(o.y, 0.f);
      o.z = fmaxf(o.z, 0.f);
      o.w = fmaxf(o.w, 0.f);
    }
    if (OUTBF16) {
      unsigned short* ob = (unsigned short*)outp + (size_t)n * 128 + 4 * l;
      uint2 pk;
      pk.x = pack_bf16_2(o.x, o.y);
      pk.y = pack_bf16_2(o.z, o.w);
      *(uint2*)ob = pk;
    } else {
      float* of = (float*)outp + (size_t)n * 128 + 4 * l;
      *(float4*)of = o;
    }
  }
}

// ---------------- global mean pool (batch sorted) ----------------

__global__ __launch_bounds__(128) void pool_kernel(const float* __restrict__ h,
                                                   const int* __restrict__ batch,
                                                   float* __restrict__ out, int N) {
  int g = blockIdx.x;
  int lo = 0, hi = N;
  while (lo < hi) { int mid = (lo + hi) >> 1; if (batch[mid] < g) lo = mid + 1; else hi = mid; }
  int s0 = lo;
  hi = N;
  while (lo < hi) { int mid = (lo + hi) >> 1; if (batch[mid] <= g) lo = mid + 1; else hi = mid; }
  int s1 = lo;
  int j = threadIdx.x;
  float acc = 0.f;
  for (int n = s0; n < s1; ++n) acc += h[(size_t)n * 128 + j];
  out[(size_t)g * 128 + j] = acc / fmaxf((float)(s1 - s0), 1.f);
}

// ---------------- launch ----------------

extern "C" void kernel_launch(void* const* d_in, const int* in_sizes, int n_in,
                              void* d_out, int out_size, void* d_ws, size_t ws_size,
                              hipStream_t stream) {
  const float* x = (const float*)d_in[0];
  const int* ei = (const int*)d_in[1];
  const int* batch = (const int*)d_in[2];
  const float* Wq1 = (const float*)d_in[3];
  const float* bq1 = (const float*)d_in[4];
  const float* Wk1 = (const float*)d_in[5];
  const float* bk1 = (const float*)d_in[6];
  const float* Wv1 = (const float*)d_in[7];
  const float* bv1 = (const float*)d_in[8];
  const float* Ws1 = (const float*)d_in[9];
  const float* bs1 = (const float*)d_in[10];
  const float* Wq2 = (const float*)d_in[11];
  const float* bq2 = (const float*)d_in[12];
  const float* Wk2 = (const float*)d_in[13];
  const float* bk2 = (const float*)d_in[14];
  const float* Wv2 = (const float*)d_in[15];
  const float* bv2 = (const float*)d_in[16];
  const float* Ws2 = (const float*)d_in[17];
  const float* bs2 = (const float*)d_in[18];

  int N = in_sizes[0] / D1;  // 50000
  int E = in_sizes[1] / 2;   // 800000
  int NG = out_size / DH;    // 512
  const int* src = ei;
  const int* dst = ei + E;

  char* ws = (char*)d_ws;
  unsigned short* qb = (unsigned short*)ws;  ws += (size_t)N * DH * 2;  // bf16 q (pre-scaled)
  unsigned short* kvb = (unsigned short*)ws; ws += (size_t)N * DH * 4;  // bf16 k|v interleaved
  float* s = (float*)ws;             ws += (size_t)N * DH * 4;   // skip / h2 (in-place)
  unsigned short* h1b = (unsigned short*)ws; ws += (size_t)N * DH * 2;  // bf16 h1
  unsigned short* xb = (unsigned short*)ws;  ws += (size_t)N * D1 * 2;  // bf16 x
  unsigned short* wt[8];
  for (int m = 0; m < 8; ++m) {
    int din = (m < 4) ? 64 : 128;
    wt[m] = (unsigned short*)ws;
    ws += (size_t)128 * din * 2;
  }
  ws = (char*)(((size_t)ws + 255) & ~(size_t)255);
  int* rowptr = (int*)ws; ws += (size_t)(N + 1) * 4;
  ws = (char*)(((size_t)ws + 255) & ~(size_t)255);
  int* deg = (int*)ws;  ws += (size_t)N * 4;
  int* fill = (int*)ws; ws += (size_t)N * 4;   // contiguous with deg: one memset
  int* incl = (int*)ws; ws += (size_t)N * 4;
  int* offs = (int*)ws; ws += 1024;
  int* sums = (int*)ws; ws += 1024;
  int* csr = (int*)ws;  ws += (size_t)E * 4;

  int nch = (N + SCHUNK - 1) / SCHUNK;

  hipMemsetAsync(deg, 0, (size_t)2 * N * 4, stream);  // deg + fill

  hist_kernel<<<(E + 255) / 256, 256, 0, stream>>>(dst, deg, E);
  scan_chunks<<<nch, 256, 0, stream>>>(deg, incl, sums, N);
  scan_top<<<1, 64, 0, stream>>>(sums, offs, nch);
  finalize_rowptr<<<(N + 255) / 256, 256, 0, stream>>>(incl, offs, rowptr, N);
  fill_csr<<<(E + 255) / 256, 256, 0, stream>>>(src, dst, rowptr, fill, csr, E);

  prep_w<<<dim3(64, 9), 256, 0, stream>>>(Wq1, Wk1, Wv1, Ws1, Wq2, Wk2, Wv2, Ws2,
                                          wt[0], wt[1], wt[2], wt[3],
                                          wt[4], wt[5], wt[6], wt[7],
                                          (const float4*)x, (uint2*)xb, N * D1 / 4);

  int nb = (N + 63) / 64;
  // layer 1
  gemm4<D1><<<dim3(nb, 4), 256, 0, stream>>>(xb, N, wt[0], bq1, wt[1], bk1,
                                             wt[2], bv1, wt[3], bs1, qb, kvb, s);
  edge_agg2<true, true><<<(N + 3) / 4, 256, 0, stream>>>(
      qb, (const uint4*)kvb, rowptr, csr, s, h1b, N);
  // layer 2
  gemm4<DH><<<dim3(nb, 4), 256, 0, stream>>>(h1b, N, wt[4], bq2, wt[5], bk2,
                                             wt[6], bv2, wt[7], bs2, qb, kvb, s);
  edge_agg2<false, false><<<(N + 3) / 4, 256, 0, stream>>>(
      qb, (const uint4*)kvb, rowptr, csr, s, s, N);
  // mean pool
  pool_kernel<<<NG, 128, 0, stream>>>(s, batch, (float*)d_out, N);
}

// Round 7
// 345.752 us; speedup vs baseline: 1.0529x; 1.0529x over previous
//
#include <hip/hip_runtime.h>
#include <math.h>

// DrugEncoder: 2x TransformerConv (heads=1) + global mean pool.
// N=50000 nodes, E=800000 edges, G=512 graphs, D_IN=64, D_HID=D_EMB=128.
//
// R7: gemm4 -> 128-row tiles / 512 threads (2x MFMA per staged tile),
//     scan_top folded into finalize_rowptr, edge_agg prefetch depth 3.

constexpr int D1 = 64;
constexpr int DH = 128;
constexpr int SCHUNK = 1024;
constexpr float QSCALE = 0.08838834764831845f;  // 1/sqrt(128)

typedef __attribute__((ext_vector_type(8))) short short8v;
typedef __attribute__((ext_vector_type(4))) float f32x4;

__device__ inline unsigned short bf16r(float f) {
  unsigned u = __float_as_uint(f);
  return (unsigned short)((u + 0x7fffu + ((u >> 16) & 1u)) >> 16);
}

__device__ inline unsigned pack_bf16_2(float a, float b) {
  return (unsigned)bf16r(a) | ((unsigned)bf16r(b) << 16);
}

// ---------------- CSR build ----------------

__global__ void hist_kernel(const int* __restrict__ dst, int* __restrict__ deg, int E) {
  int e = blockIdx.x * blockDim.x + threadIdx.x;
  if (e < E) atomicAdd(&deg[dst[e]], 1);
}

__global__ void scan_chunks(const int* __restrict__ deg, int* __restrict__ incl,
                            int* __restrict__ sums, int N) {
  __shared__ int lds[256];
  int b = blockIdx.x, tid = threadIdx.x;
  int base = b * SCHUNK + tid * 4;
  int e0 = (base + 0 < N) ? deg[base + 0] : 0;
  int e1 = (base + 1 < N) ? deg[base + 1] : 0;
  int e2 = (base + 2 < N) ? deg[base + 2] : 0;
  int e3 = (base + 3 < N) ? deg[base + 3] : 0;
  int t0 = e0, t1 = t0 + e1, t2 = t1 + e2, t3 = t2 + e3;
  lds[tid] = t3;
  __syncthreads();
  for (int off = 1; off < 256; off <<= 1) {
    int v = (tid >= off) ? lds[tid - off] : 0;
    __syncthreads();
    lds[tid] += v;
    __syncthreads();
  }
  int excl = (tid > 0) ? lds[tid - 1] : 0;
  if (base + 0 < N) incl[base + 0] = t0 + excl;
  if (base + 1 < N) incl[base + 1] = t1 + excl;
  if (base + 2 < N) incl[base + 2] = t2 + excl;
  if (base + 3 < N) incl[base + 3] = t3 + excl;
  if (tid == 255) sums[b] = lds[255];
}

// rowptr[n+1] = incl[n] + sum(sums[0..n/SCHUNK)); ~49 L2-hit adds per thread.
__global__ void finalize_rowptr(const int* __restrict__ incl, const int* __restrict__ sums,
                                int* __restrict__ rowptr, int N) {
  int n = blockIdx.x * blockDim.x + threadIdx.x;
  if (n < N) {
    int ch = n / SCHUNK;
    int off = 0;
    for (int i = 0; i < ch; ++i) off += sums[i];
    rowptr[n + 1] = incl[n] + off;
  }
  if (n == 0) rowptr[0] = 0;
}

__global__ void fill_csr(const int* __restrict__ src, const int* __restrict__ dst,
                         const int* __restrict__ rowptr, int* __restrict__ fill,
                         int* __restrict__ csr_src, int E) {
  int e = blockIdx.x * blockDim.x + threadIdx.x;
  if (e < E) {
    int d = dst[e];
    int pos = rowptr[d] + atomicAdd(&fill[d], 1);
    csr_src[pos] = src[e];
  }
}

// ---------------- prep: W -> transposed bf16 (y<8), x -> bf16 (y==8) ----------------

__global__ void prep_w(const float* w0, const float* w1, const float* w2, const float* w3,
                       const float* w4, const float* w5, const float* w6, const float* w7,
                       unsigned short* t0, unsigned short* t1, unsigned short* t2,
                       unsigned short* t3, unsigned short* t4, unsigned short* t5,
                       unsigned short* t6, unsigned short* t7,
                       const float4* __restrict__ x, uint2* __restrict__ xb, int n4) {
  int m = blockIdx.y;
  int stride = gridDim.x * blockDim.x;
  int start = blockIdx.x * blockDim.x + threadIdx.x;
  if (m == 8) {
    for (int i = start; i < n4; i += stride) {
      float4 v = x[i];
      uint2 o;
      o.x = pack_bf16_2(v.x, v.y);
      o.y = pack_bf16_2(v.z, v.w);
      xb[i] = o;
    }
    return;
  }
  const float* W;
  unsigned short* T;
  switch (m) {
    case 0: W = w0; T = t0; break;
    case 1: W = w1; T = t1; break;
    case 2: W = w2; T = t2; break;
    case 3: W = w3; T = t3; break;
    case 4: W = w4; T = t4; break;
    case 5: W = w5; T = t5; break;
    case 6: W = w6; T = t6; break;
    default: W = w7; T = t7; break;
  }
  int din = (m < 4) ? 64 : 128;
  int total = din * 128;
  for (int i = start; i < total; i += stride) {
    int r = i >> 7, c = i & 127;  // W[r][c]
    T[c * din + r] = bf16r(W[i]);
  }
}

// ---------------- bf16 MFMA 4-way linear ----------------
// grid (ceil(N/128), 4). y: 0=q(bf16, pre-scaled) 1=k(->kv lo) 2=v(->kv hi)
// 3=skip(fp32). 512 threads = 8 waves; wave w owns rows 16w..16w+15 x 128 cols.
// A: xb[128 x DIN] bf16 LDS (stride DS=DIN+8); B: Wt_y[128 x DIN] same.
// Per wave: 8 nf x (DIN/32) ks mfma_f32_16x16x32_bf16.

template <int DIN>
__global__ __launch_bounds__(512) void gemm4(
    const unsigned short* __restrict__ xb, int N,
    const unsigned short* __restrict__ Wt0, const float* __restrict__ B0,
    const unsigned short* __restrict__ Wt1, const float* __restrict__ B1,
    const unsigned short* __restrict__ Wt2, const float* __restrict__ B2,
    const unsigned short* __restrict__ Wt3, const float* __restrict__ B3,
    unsigned short* __restrict__ Qb, unsigned short* __restrict__ KV,
    float* __restrict__ Os) {
  constexpr int DS = DIN + 8;
  __shared__ __align__(16) unsigned short As[128 * DS];
  __shared__ __align__(16) unsigned short Bs[128 * DS];
  const unsigned short* Wt;
  const float* Bias;
  int y = blockIdx.y;
  switch (y) {
    case 0: Wt = Wt0; Bias = B0; break;
    case 1: Wt = Wt1; Bias = B1; break;
    case 2: Wt = Wt2; Bias = B2; break;
    default: Wt = Wt3; Bias = B3; break;
  }
  int tid = threadIdx.x;
  int n0 = blockIdx.x * 128;

  constexpr int CPR = DIN / 8;          // 16B chunks per row
  constexpr int ACH = 128 * CPR;        // chunks per tile
#pragma unroll
  for (int c = tid; c < ACH; c += 512) {
    int row = c / CPR, c8 = c - row * CPR;
    int n = n0 + row;
    uint4 val = {0u, 0u, 0u, 0u};
    if (n < N) val = *(const uint4*)&xb[(size_t)n * DIN + c8 * 8];
    *(uint4*)&As[row * DS + c8 * 8] = val;
  }
#pragma unroll
  for (int c = tid; c < ACH; c += 512) {
    int row = c / CPR, c8 = c - row * CPR;
    uint4 val = *(const uint4*)&Wt[(size_t)row * DIN + c8 * 8];
    *(uint4*)&Bs[row * DS + c8 * 8] = val;
  }
  __syncthreads();

  int w = tid >> 6, lane = tid & 63, lr = lane & 15, lg = lane >> 4;
  constexpr int KS = DIN / 32;
  short8v a[KS];
#pragma unroll
  for (int ks = 0; ks < KS; ++ks)
    a[ks] = *(const short8v*)&As[(16 * w + lr) * DS + ks * 32 + lg * 8];

  f32x4 acc[8];
#pragma unroll
  for (int nf = 0; nf < 8; ++nf) acc[nf] = (f32x4){0.f, 0.f, 0.f, 0.f};

#pragma unroll
  for (int ks = 0; ks < KS; ++ks) {
#pragma unroll
    for (int nf = 0; nf < 8; ++nf) {
      short8v b = *(const short8v*)&Bs[(nf * 16 + lr) * DS + ks * 32 + lg * 8];
      acc[nf] = __builtin_amdgcn_mfma_f32_16x16x32_bf16(a[ks], b, acc[nf], 0, 0, 0);
    }
  }

  int rbase = n0 + 16 * w + lg * 4;
#pragma unroll
  for (int nf = 0; nf < 8; ++nf) {
    int col = nf * 16 + lr;
    float bias = Bias[col];
    if (y == 0) {
#pragma unroll
      for (int r = 0; r < 4; ++r) {
        int n = rbase + r;
        if (n < N) Qb[(size_t)n * 128 + col] = bf16r((acc[nf][r] + bias) * QSCALE);
      }
    } else if (y == 3) {
#pragma unroll
      for (int r = 0; r < 4; ++r) {
        int n = rbase + r;
        if (n < N) Os[(size_t)n * 128 + col] = acc[nf][r] + bias;
      }
    } else {
      int off = (col >> 2) * 8 + (col & 3) + ((y == 2) ? 4 : 0);
#pragma unroll
      for (int r = 0; r < 4; ++r) {
        int n = rbase + r;
        if (n < N) KV[(size_t)n * 256 + off] = bf16r(acc[nf][r] + bias);
      }
    }
  }
}

// ---------------- edge aggregation ----------------
// One wave per dst node; 2 x 32-lane deferred-max online-softmax streams over
// alternating edges (prefetch depth 3), merged at end.
// kv slot l = {k[4l..4l+3], v[4l..4l+3]} bf16; q bf16 pre-scaled.

template <bool RELU, bool OUTBF16>
__global__ __launch_bounds__(256) void edge_agg2(
    const unsigned short* __restrict__ qb, const uint4* __restrict__ kv,
    const int* __restrict__ rowptr, const int* __restrict__ csr_src,
    const float* skip, void* outp, int N) {
  int tid = threadIdx.x;
  int lane = tid & 63;
  int wv = tid >> 6;
  int n = blockIdx.x * 4 + wv;
  if (n >= N) return;
  int g = lane >> 5;
  int l = lane & 31;
  uint2 qp = *(const uint2*)&qb[(size_t)n * 128 + 4 * l];
  float qx = __uint_as_float(qp.x << 16);
  float qy = __uint_as_float(qp.x & 0xffff0000u);
  float qz = __uint_as_float(qp.y << 16);
  float qw = __uint_as_float(qp.y & 0xffff0000u);
  int beg = rowptr[n];
  int deg = rowptr[n + 1] - beg;
  float m = -INFINITY, lsum = 0.f;
  float a0 = 0.f, a1 = 0.f, a2 = 0.f, a3 = 0.f;
  int cnt = (deg - g + 1) >> 1;
  const int* cp = csr_src + beg + g;
  uint4 kv0 = {0, 0, 0, 0}, kv1 = {0, 0, 0, 0}, kv2 = {0, 0, 0, 0};
  if (cnt >= 1) kv0 = kv[(size_t)cp[0] * 32 + l];
  if (cnt >= 2) kv1 = kv[(size_t)cp[2] * 32 + l];
  if (cnt >= 3) kv2 = kv[(size_t)cp[4] * 32 + l];
  for (int it = 0; it < cnt; ++it) {
    uint4 cur = kv0;
    kv0 = kv1;
    kv1 = kv2;
    if (it + 3 < cnt) kv2 = kv[(size_t)cp[2 * (it + 3)] * 32 + l];
    float k0 = __uint_as_float(cur.x << 16);
    float k1 = __uint_as_float(cur.x & 0xffff0000u);
    float k2 = __uint_as_float(cur.y << 16);
    float k3 = __uint_as_float(cur.y & 0xffff0000u);
    float d = qx * k0 + qy * k1 + qz * k2 + qw * k3;
#pragma unroll
    for (int off = 1; off < 32; off <<= 1) d += __shfl_xor(d, off);
    float v0 = __uint_as_float(cur.z << 16);
    float v1 = __uint_as_float(cur.z & 0xffff0000u);
    float v2 = __uint_as_float(cur.w << 16);
    float v3 = __uint_as_float(cur.w & 0xffff0000u);
    if (d > m + 8.f) {        // rare: new max beyond slack -> rescale
      float cf = __expf(m - d);
      lsum = lsum * cf + 1.f;
      a0 = a0 * cf + v0;
      a1 = a1 * cf + v1;
      a2 = a2 * cf + v2;
      a3 = a3 * cf + v3;
      m = d;
    } else {                  // common: accumulate against stale max
      float ef = __expf(d - m);
      lsum += ef;
      a0 += ef * v0;
      a1 += ef * v1;
      a2 += ef * v2;
      a3 += ef * v3;
    }
  }
  float m2 = __shfl_xor(m, 32);
  float L2 = __shfl_xor(lsum, 32);
  float b0 = __shfl_xor(a0, 32);
  float b1 = __shfl_xor(a1, 32);
  float b2 = __shfl_xor(a2, 32);
  float b3 = __shfl_xor(a3, 32);
  if (lane < 32) {
    float ox0 = 0.f, ox1 = 0.f, ox2 = 0.f, ox3 = 0.f;
    if (deg > 0) {
      float M = fmaxf(m, m2);
      float c1 = __expf(m - M);
      float c2 = __expf(m2 - M);
      float rl = 1.f / (lsum * c1 + L2 * c2 + 1e-16f);
      ox0 = (a0 * c1 + b0 * c2) * rl;
      ox1 = (a1 * c1 + b1 * c2) * rl;
      ox2 = (a2 * c1 + b2 * c2) * rl;
      ox3 = (a3 * c1 + b3 * c2) * rl;
    }
    const float* sp = skip + (size_t)n * 128 + 4 * l;
    float4 o = *(const float4*)sp;
    o.x += ox0; o.y += ox1; o.z += ox2; o.w += ox3;
    if (RELU) {
      o.x = fmaxf(o.x, 0.f);
      o.y = fmaxf(o.y, 0.f);
      o.z = fmaxf(o.z, 0.f);
      o.w = fmaxf(o.w, 0.f);
    }
    if (OUTBF16) {
      unsigned short* ob = (unsigned short*)outp + (size_t)n * 128 + 4 * l;
      uint2 pk;
      pk.x = pack_bf16_2(o.x, o.y);
      pk.y = pack_bf16_2(o.z, o.w);
      *(uint2*)ob = pk;
    } else {
      float* of = (float*)outp + (size_t)n * 128 + 4 * l;
      *(float4*)of = o;
    }
  }
}

// ---------------- global mean pool (batch sorted) ----------------

__global__ __launch_bounds__(128) void pool_kernel(const float* __restrict__ h,
                                                   const int* __restrict__ batch,
                                                   float* __restrict__ out, int N) {
  int g = blockIdx.x;
  int lo = 0, hi = N;
  while (lo < hi) { int mid = (lo + hi) >> 1; if (batch[mid] < g) lo = mid + 1; else hi = mid; }
  int s0 = lo;
  hi = N;
  while (lo < hi) { int mid = (lo + hi) >> 1; if (batch[mid] <= g) lo = mid + 1; else hi = mid; }
  int s1 = lo;
  int j = threadIdx.x;
  float acc = 0.f;
  for (int n = s0; n < s1; ++n) acc += h[(size_t)n * 128 + j];
  out[(size_t)g * 128 + j] = acc / fmaxf((float)(s1 - s0), 1.f);
}

// ---------------- launch ----------------

extern "C" void kernel_launch(void* const* d_in, const int* in_sizes, int n_in,
                              void* d_out, int out_size, void* d_ws, size_t ws_size,
                              hipStream_t stream) {
  const float* x = (const float*)d_in[0];
  const int* ei = (const int*)d_in[1];
  const int* batch = (const int*)d_in[2];
  const float* Wq1 = (const float*)d_in[3];
  const float* bq1 = (const float*)d_in[4];
  const float* Wk1 = (const float*)d_in[5];
  const float* bk1 = (const float*)d_in[6];
  const float* Wv1 = (const float*)d_in[7];
  const float* bv1 = (const float*)d_in[8];
  const float* Ws1 = (const float*)d_in[9];
  const float* bs1 = (const float*)d_in[10];
  const float* Wq2 = (const float*)d_in[11];
  const float* bq2 = (const float*)d_in[12];
  const float* Wk2 = (const float*)d_in[13];
  const float* bk2 = (const float*)d_in[14];
  const float* Wv2 = (const float*)d_in[15];
  const float* bv2 = (const float*)d_in[16];
  const float* Ws2 = (const float*)d_in[17];
  const float* bs2 = (const float*)d_in[18];

  int N = in_sizes[0] / D1;  // 50000
  int E = in_sizes[1] / 2;   // 800000
  int NG = out_size / DH;    // 512
  const int* src = ei;
  const int* dst = ei + E;

  char* ws = (char*)d_ws;
  unsigned short* qb = (unsigned short*)ws;  ws += (size_t)N * DH * 2;  // bf16 q (pre-scaled)
  unsigned short* kvb = (unsigned short*)ws; ws += (size_t)N * DH * 4;  // bf16 k|v interleaved
  float* s = (float*)ws;             ws += (size_t)N * DH * 4;   // skip / h2 (in-place)
  unsigned short* h1b = (unsigned short*)ws; ws += (size_t)N * DH * 2;  // bf16 h1
  unsigned short* xb = (unsigned short*)ws;  ws += (size_t)N * D1 * 2;  // bf16 x
  unsigned short* wt[8];
  for (int m = 0; m < 8; ++m) {
    int din = (m < 4) ? 64 : 128;
    wt[m] = (unsigned short*)ws;
    ws += (size_t)128 * din * 2;
  }
  ws = (char*)(((size_t)ws + 255) & ~(size_t)255);
  int* rowptr = (int*)ws; ws += (size_t)(N + 1) * 4;
  ws = (char*)(((size_t)ws + 255) & ~(size_t)255);
  int* deg = (int*)ws;  ws += (size_t)N * 4;
  int* fill = (int*)ws; ws += (size_t)N * 4;   // contiguous with deg: one memset
  int* incl = (int*)ws; ws += (size_t)N * 4;
  int* sums = (int*)ws; ws += 1024;
  int* csr = (int*)ws;  ws += (size_t)E * 4;

  int nch = (N + SCHUNK - 1) / SCHUNK;

  hipMemsetAsync(deg, 0, (size_t)2 * N * 4, stream);  // deg + fill

  hist_kernel<<<(E + 255) / 256, 256, 0, stream>>>(dst, deg, E);
  scan_chunks<<<nch, 256, 0, stream>>>(deg, incl, sums, N);
  finalize_rowptr<<<(N + 255) / 256, 256, 0, stream>>>(incl, sums, rowptr, N);
  fill_csr<<<(E + 255) / 256, 256, 0, stream>>>(src, dst, rowptr, fill, csr, E);

  prep_w<<<dim3(64, 9), 256, 0, stream>>>(Wq1, Wk1, Wv1, Ws1, Wq2, Wk2, Wv2, Ws2,
                                          wt[0], wt[1], wt[2], wt[3],
                                          wt[4], wt[5], wt[6], wt[7],
                                          (const float4*)x, (uint2*)xb, N * D1 / 4);

  int nb = (N + 127) / 128;
  // layer 1
  gemm4<D1><<<dim3(nb, 4), 512, 0, stream>>>(xb, N, wt[0], bq1, wt[1], bk1,
                                             wt[2], bv1, wt[3], bs1, qb, kvb, s);
  edge_agg2<true, true><<<(N + 3) / 4, 256, 0, stream>>>(
      qb, (const uint4*)kvb, rowptr, csr, s, h1b, N);
  // layer 2
  gemm4<DH><<<dim3(nb, 4), 512, 0, stream>>>(h1b, N, wt[4], bq2, wt[5], bk2,
                                             wt[6], bv2, wt[7], bs2, qb, kvb, s);
  edge_agg2<false, false><<<(N + 3) / 4, 256, 0, stream>>>(
      qb, (const uint4*)kvb, rowptr, csr, s, s, N);
  // mean pool
  pool_kernel<<<NG, 128, 0, stream>>>(s, batch, (float*)d_out, N);
}